// Round 11
// baseline (2692.639 us; speedup 1.0000x reference)
//
#include <hip/hip_runtime.h>
#include <hip/hip_bf16.h>

// Encoder: e = embed[x]; q = LSTM_q(e); k = LSTM_k(e); A = q @ k^T (per batch)
// B=32, T=512, D=512, NUM_TOKENS=14.
//
// R11 = R10 + cross-group software pipelining. Per phase (group g, step t):
//   1) poll other group pg's flags; ISSUE pg's h stage loads (async)
//   2) MFMA group g from h_lds[g] (load RT hides under this)
//   3) barrier; vmcnt(0); ds_write prefetch -> h_lds[pg]
//   4) tail g: gates+pre -> c,h; publish (sc0sc1) + drain; hist store
//   5) barrier; tid0 flag store
// 2 barriers/phase (was 3) and zero serialized stage RT.
// Flag protocol and 2-phase hbf safety unchanged from R10 (proven).

#define TB 32
#define TT 512
#define TD 512
#define NTOK 14

typedef __attribute__((ext_vector_type(8))) short short8;
typedef __attribute__((ext_vector_type(4))) float f32x4;

__device__ __forceinline__ float fsigmoid(float v) { return 1.f / (1.f + __expf(-v)); }
__device__ __forceinline__ float ftanh(float v) {
    float a = fabsf(v);
    float e = __expf(-2.f * a);
    float r = (1.f - e) / (1.f + e);
    return copysignf(r, v);
}
__device__ __forceinline__ unsigned int f2bf(float f) {
    __hip_bfloat16 h = __float2bfloat16(f);
    return (unsigned int)__builtin_bit_cast(unsigned short, h);
}

// device-coherent 16B load (L1/L2 bypass -> reads coherent point)
__device__ __forceinline__ short8 load16_coh(const unsigned short* p) {
    short8 r;
    asm volatile("global_load_dwordx4 %0, %1, off sc0 sc1" : "=v"(r) : "v"(p));
    return r;
}
// device-coherent 2B/4B stores (write-through, fire-and-forget)
__device__ __forceinline__ void store2_coh(unsigned short* p, unsigned int v) {
    asm volatile("global_store_short %0, %1, off sc0 sc1" :: "v"(p), "v"(v) : "memory");
}
__device__ __forceinline__ void store4_coh(unsigned int* p, unsigned int v) {
    asm volatile("global_store_dword %0, %1, off sc0 sc1" :: "v"(p), "v"(v) : "memory");
}
// coherent dword load with completed wait (for flag polling)
__device__ __forceinline__ unsigned int load4_coh(const unsigned int* p) {
    unsigned int r;
    asm volatile("global_load_dword %0, %1, off sc0 sc1\n\ts_waitcnt vmcnt(0)"
                 : "=v"(r) : "v"(p) : "memory");
    return r;
}

// ---- pre_tab[l][tok][2048] = embed[tok] @ W_ih_l^T + b_ih_l + b_hh_l ----
__global__ __launch_bounds__(256) void pre_tab_kernel(
    const float* __restrict__ embed,
    const float* __restrict__ Wih_q, const float* __restrict__ bih_q, const float* __restrict__ bhh_q,
    const float* __restrict__ Wih_k, const float* __restrict__ bih_k, const float* __restrict__ bhh_k,
    float* __restrict__ pre)
{
    int idx = blockIdx.x * 256 + threadIdx.x;   // 2*14*2048 = 57344 exactly
    int l = idx / (NTOK * 4 * TD);
    int r = idx % (NTOK * 4 * TD);
    int tok = r / (4 * TD), j = r % (4 * TD);
    const float* Wih = l ? Wih_k : Wih_q;
    float acc = l ? (bih_k[j] + bhh_k[j]) : (bih_q[j] + bhh_q[j]);
    const float4* e4 = (const float4*)(embed + (size_t)tok * TD);
    const float4* w4 = (const float4*)(Wih + (size_t)j * TD);
    for (int t2 = 0; t2 < TD / 4; ++t2) {
        float4 e = e4[t2], w = w4[t2];
        acc += e.x * w.x + e.y * w.y + e.z * w.z + e.w * w.w;
    }
    pre[idx] = acc;
}

__global__ void init_flags(unsigned int* flags) { flags[threadIdx.x] = 0; }

// ---- persistent LSTM: 64 WGs (wg>>5 = lstm l, (wg&31)*16 = dim base) ----
// flags: [l][group][32 wid]; hbf: [l][phase][b 0..31][512] bf16
__global__ __launch_bounds__(512) void lstm_persist(
    const float* __restrict__ Whh_q, const float* __restrict__ Whh_k,
    const float* __restrict__ pre,
    const int* __restrict__ x,
    float* __restrict__ qout, float* __restrict__ kout,
    unsigned short* __restrict__ hbf,
    unsigned int* __restrict__ flags)
{
    __shared__ unsigned short w_lds[64][512];    // 64 KB, 16B-chunk XOR swizzled
    __shared__ unsigned short h_lds[2][16][512]; // 32 KB, double-buffered by group
    __shared__ float          g_lds[2][64][17];  // 8.7 KB, [K-half][gate-row][b_local]
    __shared__ unsigned char  x_lds[TB * TT];    // 16 KB
    __shared__ float          pre_lds[NTOK][64]; // 3.5 KB, [tok][gate*16+dd]

    int wg  = blockIdx.x;
    int l   = wg >> 5;
    int wid = wg & 31;
    int d0  = wid << 4;                          // 16 dims per WG
    int tid = threadIdx.x;
    int lane = tid & 63;
    int wv = tid >> 6;                           // 8 waves
    int rt = wv & 3;                             // gate-row tile (rows rt*16..)
    int kh = wv >> 2;                            // K-half (256 each)

    const float* Whh = l ? Whh_k : Whh_q;
    float* hist = l ? kout : qout;
    unsigned short* hb_l = hbf + (size_t)l * 2 * TB * TD;
    unsigned int* fl = flags + l * 64;

    // ---- stage W slice: 64 gate-rows (gate*16+dd), f32->bf16, XOR swizzle ----
    {
        int r = tid >> 3;                        // 0..63, 8 threads/row
        const float* src = Whh + (size_t)((r >> 4) * TD + d0 + (r & 15)) * TD;
#pragma unroll
        for (int i = 0; i < 8; ++i) {
            int c = (tid & 7) + 8 * i;           // chunk 0..63 (8 bf16 = 16B)
            float4 a = ((const float4*)src)[c * 2];
            float4 b4 = ((const float4*)src)[c * 2 + 1];
            unsigned short* dst = &w_lds[r][(c ^ (r & 7)) * 8];
            dst[0] = (unsigned short)f2bf(a.x); dst[1] = (unsigned short)f2bf(a.y);
            dst[2] = (unsigned short)f2bf(a.z); dst[3] = (unsigned short)f2bf(a.w);
            dst[4] = (unsigned short)f2bf(b4.x); dst[5] = (unsigned short)f2bf(b4.y);
            dst[6] = (unsigned short)f2bf(b4.z); dst[7] = (unsigned short)f2bf(b4.w);
        }
    }
    for (int i = tid; i < TB * TT; i += 512) x_lds[i] = (unsigned char)x[i];
    for (int i = tid; i < NTOK * 64; i += 512) {
        int tok = i >> 6, j = i & 63;            // j = gate*16 + dd
        pre_lds[tok][j] = pre[((size_t)l * NTOK + tok) * (4 * TD) + (j >> 4) * TD + d0 + (j & 15)];
    }
    __syncthreads();

    int b  = tid >> 4, dd = tid & 15;            // tail mapping (b 0..31)
    int row = tid >> 5, c0 = tid & 31;           // prefetch mapping (16 rows x 32 chunks)
    float creg = 0.f;

    // ---- t=0: tail only (c=h=0 before), all batches; publish both groups ----
    {
        int tok = x_lds[b * TT];
        float i_ = fsigmoid(pre_lds[tok][dd]);
        float f_ = fsigmoid(pre_lds[tok][16 + dd]);
        float g_ = ftanh(pre_lds[tok][32 + dd]);
        float o_ = fsigmoid(pre_lds[tok][48 + dd]);
        creg = i_ * g_;
        float h = o_ * ftanh(creg);
        store2_coh(hb_l + (size_t)b * TD + d0 + dd, f2bf(h));
        asm volatile("s_waitcnt vmcnt(0)" ::: "memory");
        hist[((size_t)b * TT) * TD + d0 + dd] = h;
    }
    __syncthreads();
    if (tid == 0) { store4_coh(fl + wid, 1u); store4_coh(fl + 32 + wid, 1u); }

    // ---- prologue: stage h_A(0) -> h_lds[0] ----
    {
        const unsigned int* fp = fl + (lane & 31);
        for (;;) {
            unsigned int v = load4_coh(fp);
            if (__all((int)(v >= 1u))) break;
            __builtin_amdgcn_s_sleep(1);
        }
        const unsigned short* src = hb_l + (size_t)row * TD;
        short8 p0 = load16_coh(src + c0 * 8);
        short8 p1 = load16_coh(src + (c0 + 32) * 8);
        asm volatile("s_waitcnt vmcnt(0)" ::: "memory");
        __builtin_amdgcn_sched_barrier(0);
        *(short8*)&h_lds[0][row][(c0 ^ (row & 7)) * 8] = p0;
        *(short8*)&h_lds[0][row][((c0 + 32) ^ (row & 7)) * 8] = p1;
    }
    __syncthreads();

    for (int t = 1; t < TT; ++t) {
#pragma unroll
        for (int g = 0; g < 2; ++g) {
            int pg = g ^ 1;
            int pt = (g == 0) ? (t - 1) : t;     // step of the data we prefetch
            bool doPref = !(g == 1 && t == TT - 1);
            short8 p0, p1;
            if (doPref) {
                // poll other group's producers, then ISSUE loads (no wait)
                const unsigned int* fp = fl + pg * 32 + (lane & 31);
                unsigned int need = (unsigned int)(pt + 1);
                for (;;) {
                    unsigned int v = load4_coh(fp);
                    if (__all((int)(v >= need))) break;
                    __builtin_amdgcn_s_sleep(1);
                }
                const unsigned short* src = hb_l + ((size_t)(pt & 1) * TB + pg * 16 + row) * TD;
                p0 = load16_coh(src + c0 * 8);
                p1 = load16_coh(src + (c0 + 32) * 8);
            }
            // MFMA group g from h_lds[g]: wave (rt, kh), tile 16 rows x 16 b, K=256
            {
                f32x4 acc = {0.f, 0.f, 0.f, 0.f};
                int rr = rt * 16 + (lane & 15);
                int hr = lane & 15;
#pragma unroll
                for (int j = 0; j < 8; ++j) {
                    int kk = kh * 8 + j;
                    int c = kk * 4 + (lane >> 4);
                    short8 a  = *(const short8*)&h_lds[g][hr][(c ^ (hr & 7)) * 8];
                    short8 bf = *(const short8*)&w_lds[rr][(c ^ (rr & 7)) * 8];
                    acc = __builtin_amdgcn_mfma_f32_16x16x32_bf16(a, bf, acc, 0, 0, 0);
                }
                int gb = (lane >> 4) << 2;
#pragma unroll
                for (int r2 = 0; r2 < 4; ++r2) g_lds[kh][rr][gb + r2] = acc[r2];
            }
            __syncthreads();                      // g_lds ready; h_lds[pg] readers done
            if (doPref) {                         // loads have had the whole MFMA to land
                asm volatile("s_waitcnt vmcnt(0)" ::: "memory");
                __builtin_amdgcn_sched_barrier(0);
                *(short8*)&h_lds[pg][row][(c0 ^ (row & 7)) * 8] = p0;
                *(short8*)&h_lds[pg][row][((c0 + 32) ^ (row & 7)) * 8] = p1;
            }
            if ((b >> 4) == g) {                  // tail for this group's batches
                int bl = b & 15;
                int tok = x_lds[b * TT + t];
                float gi = g_lds[0][dd][bl]      + g_lds[1][dd][bl]      + pre_lds[tok][dd];
                float gf = g_lds[0][16 + dd][bl] + g_lds[1][16 + dd][bl] + pre_lds[tok][16 + dd];
                float gg = g_lds[0][32 + dd][bl] + g_lds[1][32 + dd][bl] + pre_lds[tok][32 + dd];
                float go = g_lds[0][48 + dd][bl] + g_lds[1][48 + dd][bl] + pre_lds[tok][48 + dd];
                float i_ = fsigmoid(gi), f_ = fsigmoid(gf), g2 = ftanh(gg), o_ = fsigmoid(go);
                creg = f_ * creg + i_ * g2;
                float h = o_ * ftanh(creg);
                store2_coh(hb_l + (size_t)((t & 1) * TB + b) * TD + d0 + dd, f2bf(h));
                asm volatile("s_waitcnt vmcnt(0)" ::: "memory");   // drain publish
                hist[((size_t)b * TT + t) * TD + d0 + dd] = h;     // lazy f32 (after drain)
            }
            __syncthreads();                      // drains + h_lds[pg] writes complete
            if (tid == 0) store4_coh(fl + g * 32 + wid, (unsigned int)(t + 1));
        }
    }
}

// ---- A[b] = q[b] @ k[b]^T, f32, 64x64 tile / WG, 4x4 per thread ----
__global__ __launch_bounds__(256) void qk_gemm(
    const float* __restrict__ q, const float* __restrict__ k, float* __restrict__ A)
{
    __shared__ float qs[64][68];
    __shared__ float ks[64][68];
    int b = blockIdx.y;
    int t0 = (blockIdx.x >> 3) * 64;
    int s0 = (blockIdx.x & 7) * 64;
    const float* qb = q + (size_t)b * TT * TD;
    const float* kb = k + (size_t)b * TT * TD;
    int tid = threadIdx.x;
    int ty = tid >> 4, tx = tid & 15;
    float accr[4][4] = {};
    for (int k0 = 0; k0 < TD; k0 += 64) {
        for (int i = tid; i < 64 * 16; i += 256) {
            int r = i >> 4, c4 = i & 15;
            ((float4*)&qs[r][0])[c4] = ((const float4*)(qb + (size_t)(t0 + r) * TD + k0))[c4];
            ((float4*)&ks[r][0])[c4] = ((const float4*)(kb + (size_t)(s0 + r) * TD + k0))[c4];
        }
        __syncthreads();
#pragma unroll 4
        for (int kk = 0; kk < 64; kk += 4) {
            float4 qv[4], kv[4];
#pragma unroll
            for (int i = 0; i < 4; ++i) qv[i] = *(const float4*)&qs[ty * 4 + i][kk];
#pragma unroll
            for (int j = 0; j < 4; ++j) kv[j] = *(const float4*)&ks[tx * 4 + j][kk];
#pragma unroll
            for (int i = 0; i < 4; ++i)
#pragma unroll
                for (int j = 0; j < 4; ++j)
                    accr[i][j] += qv[i].x * kv[j].x + qv[i].y * kv[j].y
                                + qv[i].z * kv[j].z + qv[i].w * kv[j].w;
        }
        __syncthreads();
    }
    for (int i = 0; i < 4; ++i)
        for (int j = 0; j < 4; ++j)
            A[(size_t)b * TT * TT + (size_t)(t0 + ty * 4 + i) * TT + (s0 + tx * 4 + j)] = accr[i][j];
}

extern "C" void kernel_launch(void* const* d_in, const int* in_sizes, int n_in,
                              void* d_out, int out_size, void* d_ws, size_t ws_size,
                              hipStream_t stream)
{
    const int*   x      = (const int*)d_in[0];
    const float* embed  = (const float*)d_in[1];
    const float* Wih_q  = (const float*)d_in[2];
    const float* Whh_q  = (const float*)d_in[3];
    const float* bih_q  = (const float*)d_in[4];
    const float* bhh_q  = (const float*)d_in[5];
    const float* Wih_k  = (const float*)d_in[6];
    const float* Whh_k  = (const float*)d_in[7];
    const float* bih_k  = (const float*)d_in[8];
    const float* bhh_k  = (const float*)d_in[9];

    float* ws   = (float*)d_ws;
    float* q    = ws;                                   // 8388608 f
    float* kbuf = q + (size_t)TB * TT * TD;             // 8388608 f
    float* pre  = kbuf + (size_t)TB * TT * TD;          // 57344 f
    unsigned short* hbf = (unsigned short*)(pre + 2 * NTOK * 4 * TD);  // 65536 us
    unsigned int* flags = (unsigned int*)(hbf + 65536); // 128 u32

    init_flags<<<1, 128, 0, stream>>>(flags);
    pre_tab_kernel<<<224, 256, 0, stream>>>(embed, Wih_q, bih_q, bhh_q,
                                            Wih_k, bih_k, bhh_k, pre);
    lstm_persist<<<64, 512, 0, stream>>>(Whh_q, Whh_k, pre, x, q, kbuf, hbf, flags);
    dim3 g(64, 32);
    qk_gemm<<<g, 256, 0, stream>>>(q, kbuf, (float*)d_out);
}

// Round 12
// 1701.034 us; speedup vs baseline: 1.5829x; 1.5829x over previous
//
#include <hip/hip_runtime.h>
#include <hip/hip_bf16.h>

// Encoder: e = embed[x]; q = LSTM_q(e); k = LSTM_k(e); A = q @ k^T (per batch)
// B=32, T=512, D=512, NUM_TOKENS=14.
//
// R12: one recurrence chain per WG. 128 WGs = (l, batch-group g, 16-dim slice).
// Batch groups are independent -> separate WGs, zero serialization between
// them. Sync = R7's tag-in-word (bf16<<16 | step+1): consumer polls the data
// itself (ONE device RT/step, no flags, no drains). Storm-proofing from R10:
// deduped LDS staging, convergent waves, stale-only reissue, s_sleep.
// 2-phase hbf overwrite safety: P writes h(t+1) only after polling FULL h(t),
// which requires every group member completed step t, hence finished reading
// h(t-1) (the slot being overwritten). Proof as R7, per group.

#define TB 32
#define TT 512
#define TD 512
#define NTOK 14

typedef __attribute__((ext_vector_type(8))) short short8;
typedef __attribute__((ext_vector_type(4))) float f32x4;
typedef __attribute__((ext_vector_type(4))) unsigned int u32x4;

__device__ __forceinline__ float fsigmoid(float v) { return 1.f / (1.f + __expf(-v)); }
__device__ __forceinline__ float ftanh(float v) {
    float a = fabsf(v);
    float e = __expf(-2.f * a);
    float r = (1.f - e) / (1.f + e);
    return copysignf(r, v);
}
__device__ __forceinline__ unsigned int f2bf(float f) {
    __hip_bfloat16 h = __float2bfloat16(f);
    return (unsigned int)__builtin_bit_cast(unsigned short, h);
}

// device-coherent 16B load (L1/L2 bypass -> reads coherent point)
__device__ __forceinline__ u32x4 load16_coh(const unsigned int* p) {
    u32x4 r;
    asm volatile("global_load_dwordx4 %0, %1, off sc0 sc1" : "=v"(r) : "v"(p));
    return r;
}
// device-coherent 4B store (write-through, fire-and-forget)
__device__ __forceinline__ void store4_coh(unsigned int* p, unsigned int v) {
    asm volatile("global_store_dword %0, %1, off sc0 sc1" :: "v"(p), "v"(v) : "memory");
}

// ---- pre_tab[l][tok][2048] = embed[tok] @ W_ih_l^T + b_ih_l + b_hh_l ----
__global__ __launch_bounds__(256) void pre_tab_kernel(
    const float* __restrict__ embed,
    const float* __restrict__ Wih_q, const float* __restrict__ bih_q, const float* __restrict__ bhh_q,
    const float* __restrict__ Wih_k, const float* __restrict__ bih_k, const float* __restrict__ bhh_k,
    float* __restrict__ pre)
{
    int idx = blockIdx.x * 256 + threadIdx.x;   // 2*14*2048 = 57344 exactly
    int l = idx / (NTOK * 4 * TD);
    int r = idx % (NTOK * 4 * TD);
    int tok = r / (4 * TD), j = r % (4 * TD);
    const float* Wih = l ? Wih_k : Wih_q;
    float acc = l ? (bih_k[j] + bhh_k[j]) : (bih_q[j] + bhh_q[j]);
    const float4* e4 = (const float4*)(embed + (size_t)tok * TD);
    const float4* w4 = (const float4*)(Wih + (size_t)j * TD);
    for (int t2 = 0; t2 < TD / 4; ++t2) {
        float4 e = e4[t2], w = w4[t2];
        acc += e.x * w.x + e.y * w.y + e.z * w.z + e.w * w.w;
    }
    pre[idx] = acc;
}

__global__ __launch_bounds__(256) void init_hbf(unsigned int* hbf) {
    hbf[blockIdx.x * 256 + threadIdx.x] = 0;    // 2*2*32*512 = 65536; tag 0 never matches
}

// ---- persistent LSTM: 128 WGs: l = wg>>6, g = (wg>>5)&1, wid = wg&31 ----
// hbf: [l][phase][b 0..31][512] u32 (bf16<<16 | step+1)
__global__ __launch_bounds__(256) void lstm_persist(
    const float* __restrict__ Whh_q, const float* __restrict__ Whh_k,
    const float* __restrict__ pre,
    const int* __restrict__ x,
    float* __restrict__ qout, float* __restrict__ kout,
    unsigned int* __restrict__ hbf)
{
    __shared__ unsigned short w_lds[64][512];    // 64 KB, 16B-chunk XOR swizzled
    __shared__ unsigned short h_lds[16][512];    // 16 KB, swizzled (row = batch)
    __shared__ float          g_lds[64][17];     // 4.3 KB [gate*16+dd][b_local]
    __shared__ unsigned char  x_lds[16 * TT];    // 8 KB (this group's batches)
    __shared__ float          pre_lds[NTOK][64]; // 3.5 KB [tok][gate*16+dd]

    int wg  = blockIdx.x;
    int l   = wg >> 6;
    int g   = (wg >> 5) & 1;
    int wid = wg & 31;
    int d0  = wid << 4;                          // 16 dims per WG
    int tid = threadIdx.x;
    int lane = tid & 63;
    int rt  = tid >> 6;                          // wave = gate-row tile (rows rt*16..)

    const float* Whh = l ? Whh_k : Whh_q;
    float* hist = l ? kout : qout;
    unsigned int* hb_l = hbf + (size_t)l * 2 * TB * TD;   // [phase][b][dim]

    // ---- stage W slice: 64 gate-rows (gate*16+dd), f32->bf16, XOR swizzle ----
    {
        int r = tid >> 2;                        // 0..63, 4 threads/row
        const float* src = Whh + (size_t)((r >> 4) * TD + d0 + (r & 15)) * TD;
#pragma unroll
        for (int i = 0; i < 16; ++i) {
            int c = (tid & 3) + 4 * i;           // chunk 0..63 (8 bf16 = 16B)
            float4 a = ((const float4*)src)[c * 2];
            float4 b4 = ((const float4*)src)[c * 2 + 1];
            unsigned short* dst = &w_lds[r][(c ^ (r & 7)) * 8];
            dst[0] = (unsigned short)f2bf(a.x); dst[1] = (unsigned short)f2bf(a.y);
            dst[2] = (unsigned short)f2bf(a.z); dst[3] = (unsigned short)f2bf(a.w);
            dst[4] = (unsigned short)f2bf(b4.x); dst[5] = (unsigned short)f2bf(b4.y);
            dst[6] = (unsigned short)f2bf(b4.z); dst[7] = (unsigned short)f2bf(b4.w);
        }
    }
    for (int i = tid; i < 16 * TT; i += 256)
        x_lds[i] = (unsigned char)x[(g * 16 + (i >> 9)) * TT + (i & 511)];
    for (int i = tid; i < NTOK * 64; i += 256) {
        int tok = i >> 6, j = i & 63;            // j = gate*16 + dd
        pre_lds[tok][j] = pre[((size_t)l * NTOK + tok) * (4 * TD) + (j >> 4) * TD + d0 + (j & 15)];
    }
    __syncthreads();

    int bl = tid >> 4, dd = tid & 15;            // tail mapping (16 b x 16 dd)
    int bg = g * 16 + bl;                        // global batch
    float creg = 0.f;

    // ---- t = 0: tail only (h,c = 0); publish tagged h(0) ----
    {
        int tok = x_lds[bl * TT];
        float i_ = fsigmoid(pre_lds[tok][dd]);
        float f_ = fsigmoid(pre_lds[tok][16 + dd]);
        float g_ = ftanh(pre_lds[tok][32 + dd]);
        float o_ = fsigmoid(pre_lds[tok][48 + dd]);
        creg = i_ * g_;
        float h = o_ * ftanh(creg);
        store4_coh(hb_l + (size_t)bg * TD + d0 + dd, (f2bf(h) << 16) | 1u);
        hist[((size_t)bg * TT) * TD + d0 + dd] = h;
    }

    for (int t = 1; t < TT; ++t) {
        // ---- phase 1: poll tagged h(t-1) for this group; dedupe into h_lds ----
        {
            const unsigned int e = (unsigned int)t;      // expected tag
            int row = tid >> 4;                          // 0..15 (batch within group)
            const unsigned int* hb = hb_l + (size_t)((t - 1) & 1) * TB * TD
                                          + (size_t)(g * 16 + row) * TD;
            u32x4 A0[4], B0[4];
#pragma unroll
            for (int j = 0; j < 4; ++j) {
                int m = (tid & 15) + 16 * j;             // 16B-pair unit 0..63
                A0[j] = load16_coh(hb + m * 8);
                B0[j] = load16_coh(hb + m * 8 + 4);
            }
            unsigned int st = 0xFu;
            for (;;) {
                asm volatile("s_waitcnt vmcnt(0)" ::: "memory");
                __builtin_amdgcn_sched_barrier(0);
                unsigned int ns = 0;
#pragma unroll
                for (int j = 0; j < 4; ++j) if (st & (1u << j)) {
                    unsigned int bad =
                        ((A0[j].x ^ e) | (A0[j].y ^ e) | (A0[j].z ^ e) | (A0[j].w ^ e) |
                         (B0[j].x ^ e) | (B0[j].y ^ e) | (B0[j].z ^ e) | (B0[j].w ^ e)) & 0xffffu;
                    if (bad) ns |= 1u << j;
                }
                st = ns;
                if (!__any(st != 0)) break;
#pragma unroll
                for (int j = 0; j < 4; ++j) if (st & (1u << j)) {
                    int m = (tid & 15) + 16 * j;
                    A0[j] = load16_coh(hb + m * 8);
                    B0[j] = load16_coh(hb + m * 8 + 4);
                }
                __builtin_amdgcn_s_sleep(1);
            }
#pragma unroll
            for (int j = 0; j < 4; ++j) {                // strip tags, pack bf16 pairs
                int m = (tid & 15) + 16 * j;
                u32x4 o;
                o.x = (A0[j].x >> 16) | (A0[j].y & 0xffff0000u);
                o.y = (A0[j].z >> 16) | (A0[j].w & 0xffff0000u);
                o.z = (B0[j].x >> 16) | (B0[j].y & 0xffff0000u);
                o.w = (B0[j].z >> 16) | (B0[j].w & 0xffff0000u);
                *(u32x4*)&h_lds[row][(m ^ (row & 7)) * 8] = o;
            }
        }
        __syncthreads();

        // ---- phase 2: MFMA, wave rt: 16 gate-rows x 16 batches, K=512 ----
        {
            f32x4 acc = {0.f, 0.f, 0.f, 0.f};
            int rr = rt * 16 + (lane & 15);
            int hr = lane & 15;
#pragma unroll
            for (int kk = 0; kk < 16; ++kk) {
                int c = kk * 4 + (lane >> 4);
                short8 a  = *(const short8*)&h_lds[hr][(c ^ (hr & 7)) * 8];
                short8 bf = *(const short8*)&w_lds[rr][(c ^ (rr & 7)) * 8];
                acc = __builtin_amdgcn_mfma_f32_16x16x32_bf16(a, bf, acc, 0, 0, 0);
            }
            int gb = (lane >> 4) << 2;
#pragma unroll
            for (int r2 = 0; r2 < 4; ++r2) g_lds[rr][gb + r2] = acc[r2];
        }
        __syncthreads();

        // ---- phase 3: tail; publish tagged h(t) (fire-and-forget) ----
        {
            int tok = x_lds[bl * TT + t];
            float gi = g_lds[dd][bl]      + pre_lds[tok][dd];
            float gf = g_lds[16 + dd][bl] + pre_lds[tok][16 + dd];
            float gg = g_lds[32 + dd][bl] + pre_lds[tok][32 + dd];
            float go = g_lds[48 + dd][bl] + pre_lds[tok][48 + dd];
            float i_ = fsigmoid(gi), f_ = fsigmoid(gf), g2 = ftanh(gg), o_ = fsigmoid(go);
            creg = f_ * creg + i_ * g2;
            float h = o_ * ftanh(creg);
            store4_coh(hb_l + (size_t)(t & 1) * TB * TD + (size_t)bg * TD + d0 + dd,
                       (f2bf(h) << 16) | (unsigned int)(t + 1));
            hist[((size_t)bg * TT + t) * TD + d0 + dd] = h;   // plain cached f32
        }
        // no barrier here: h_lds rewrites happen only after next poll completes,
        // and every wave passed the post-MFMA barrier (reads done) before tail.
    }
}

// ---- A[b] = q[b] @ k[b]^T, f32, 64x64 tile / WG, 4x4 per thread ----
__global__ __launch_bounds__(256) void qk_gemm(
    const float* __restrict__ q, const float* __restrict__ k, float* __restrict__ A)
{
    __shared__ float qs[64][68];
    __shared__ float ks[64][68];
    int b = blockIdx.y;
    int t0 = (blockIdx.x >> 3) * 64;
    int s0 = (blockIdx.x & 7) * 64;
    const float* qb = q + (size_t)b * TT * TD;
    const float* kb = k + (size_t)b * TT * TD;
    int tid = threadIdx.x;
    int ty = tid >> 4, tx = tid & 15;
    float accr[4][4] = {};
    for (int k0 = 0; k0 < TD; k0 += 64) {
        for (int i = tid; i < 64 * 16; i += 256) {
            int r = i >> 4, c4 = i & 15;
            ((float4*)&qs[r][0])[c4] = ((const float4*)(qb + (size_t)(t0 + r) * TD + k0))[c4];
            ((float4*)&ks[r][0])[c4] = ((const float4*)(kb + (size_t)(s0 + r) * TD + k0))[c4];
        }
        __syncthreads();
#pragma unroll 4
        for (int kk = 0; kk < 64; kk += 4) {
            float4 qv[4], kv[4];
#pragma unroll
            for (int i = 0; i < 4; ++i) qv[i] = *(const float4*)&qs[ty * 4 + i][kk];
#pragma unroll
            for (int j = 0; j < 4; ++j) kv[j] = *(const float4*)&ks[tx * 4 + j][kk];
#pragma unroll
            for (int i = 0; i < 4; ++i)
#pragma unroll
                for (int j = 0; j < 4; ++j)
                    accr[i][j] += qv[i].x * kv[j].x + qv[i].y * kv[j].y
                                + qv[i].z * kv[j].z + qv[i].w * kv[j].w;
        }
        __syncthreads();
    }
    for (int i = 0; i < 4; ++i)
        for (int j = 0; j < 4; ++j)
            A[(size_t)b * TT * TT + (size_t)(t0 + ty * 4 + i) * TT + (s0 + tx * 4 + j)] = accr[i][j];
}

extern "C" void kernel_launch(void* const* d_in, const int* in_sizes, int n_in,
                              void* d_out, int out_size, void* d_ws, size_t ws_size,
                              hipStream_t stream)
{
    const int*   x      = (const int*)d_in[0];
    const float* embed  = (const float*)d_in[1];
    const float* Wih_q  = (const float*)d_in[2];
    const float* Whh_q  = (const float*)d_in[3];
    const float* bih_q  = (const float*)d_in[4];
    const float* bhh_q  = (const float*)d_in[5];
    const float* Wih_k  = (const float*)d_in[6];
    const float* Whh_k  = (const float*)d_in[7];
    const float* bih_k  = (const float*)d_in[8];
    const float* bhh_k  = (const float*)d_in[9];

    float* ws   = (float*)d_ws;
    float* q    = ws;                                   // 8388608 f
    float* kbuf = q + (size_t)TB * TT * TD;             // 8388608 f
    float* pre  = kbuf + (size_t)TB * TT * TD;          // 57344 f
    unsigned int* hbf = (unsigned int*)(pre + 2 * NTOK * 4 * TD);  // 65536 u32

    init_hbf<<<256, 256, 0, stream>>>(hbf);
    pre_tab_kernel<<<224, 256, 0, stream>>>(embed, Wih_q, bih_q, bhh_q,
                                            Wih_k, bih_k, bhh_k, pre);
    lstm_persist<<<128, 256, 0, stream>>>(Whh_q, Whh_k, pre, x, q, kbuf, hbf);
    dim3 g2(64, 32);
    qk_gemm<<<g2, 256, 0, stream>>>(q, kbuf, (float*)d_out);
}

// Round 16
// 1651.229 us; speedup vs baseline: 1.6307x; 1.0302x over previous
//
#include <hip/hip_runtime.h>
#include <hip/hip_bf16.h>

// Encoder: e = embed[x]; q = LSTM_q(e); k = LSTM_k(e); A = q @ k^T (per batch)
// B=32, T=512, D=512, NUM_TOKENS=14.
//
// R16 = R13/R14/R15 resubmitted verbatim (all hit pod-death infra failures
// before running; round-0 stub failed identically -> not kernel-induced).
// R12's parallel-chain structure + R10's flag protocol.
// 128 WGs = (l, batch-group g, 16-dim slice); one independent chain per WG.
// Per step: poll own group's 32 flags (128 B, every wave self-gates) ->
// one clean 32 KB bf16 h fetch -> LDS -> MFMA (K=512) -> tail ->
// publish bf16 -> vmcnt(0) drain -> barrier -> tid0 flag = t+1.
// Safety (R10 proof): flag>=t from every producer implies it finished reading
// h(t-2), so overwriting slot (t&1) with h(t) races nobody.

#define TB 32
#define TT 512
#define TD 512
#define NTOK 14

typedef __attribute__((ext_vector_type(8))) short short8;
typedef __attribute__((ext_vector_type(4))) float f32x4;

__device__ __forceinline__ float fsigmoid(float v) { return 1.f / (1.f + __expf(-v)); }
__device__ __forceinline__ float ftanh(float v) {
    float a = fabsf(v);
    float e = __expf(-2.f * a);
    float r = (1.f - e) / (1.f + e);
    return copysignf(r, v);
}
__device__ __forceinline__ unsigned int f2bf(float f) {
    __hip_bfloat16 h = __float2bfloat16(f);
    return (unsigned int)__builtin_bit_cast(unsigned short, h);
}

// device-coherent 16B load (L1/L2 bypass -> reads coherent point)
__device__ __forceinline__ short8 load16_coh(const unsigned short* p) {
    short8 r;
    asm volatile("global_load_dwordx4 %0, %1, off sc0 sc1" : "=v"(r) : "v"(p));
    return r;
}
// device-coherent stores (write-through, fire-and-forget)
__device__ __forceinline__ void store2_coh(unsigned short* p, unsigned int v) {
    asm volatile("global_store_short %0, %1, off sc0 sc1" :: "v"(p), "v"(v) : "memory");
}
__device__ __forceinline__ void store4_coh(unsigned int* p, unsigned int v) {
    asm volatile("global_store_dword %0, %1, off sc0 sc1" :: "v"(p), "v"(v) : "memory");
}
// coherent dword load with completed wait (flag polling)
__device__ __forceinline__ unsigned int load4_coh(const unsigned int* p) {
    unsigned int r;
    asm volatile("global_load_dword %0, %1, off sc0 sc1\n\ts_waitcnt vmcnt(0)"
                 : "=v"(r) : "v"(p) : "memory");
    return r;
}

// ---- pre_tab[l][tok][2048] = embed[tok] @ W_ih_l^T + b_ih_l + b_hh_l ----
__global__ __launch_bounds__(256) void pre_tab_kernel(
    const float* __restrict__ embed,
    const float* __restrict__ Wih_q, const float* __restrict__ bih_q, const float* __restrict__ bhh_q,
    const float* __restrict__ Wih_k, const float* __restrict__ bih_k, const float* __restrict__ bhh_k,
    float* __restrict__ pre)
{
    int idx = blockIdx.x * 256 + threadIdx.x;   // 2*14*2048 = 57344 exactly
    int l = idx / (NTOK * 4 * TD);
    int r = idx % (NTOK * 4 * TD);
    int tok = r / (4 * TD), j = r % (4 * TD);
    const float* Wih = l ? Wih_k : Wih_q;
    float acc = l ? (bih_k[j] + bhh_k[j]) : (bih_q[j] + bhh_q[j]);
    const float4* e4 = (const float4*)(embed + (size_t)tok * TD);
    const float4* w4 = (const float4*)(Wih + (size_t)j * TD);
    for (int t2 = 0; t2 < TD / 4; ++t2) {
        float4 e = e4[t2], w = w4[t2];
        acc += e.x * w.x + e.y * w.y + e.z * w.z + e.w * w.w;
    }
    pre[idx] = acc;
}

__global__ void init_flags(unsigned int* flags) { flags[threadIdx.x] = 0; }

// ---- persistent LSTM: 128 WGs: l = wg>>6, g = (wg>>5)&1, wid = wg&31 ----
// hbf: [l][phase][b 0..31][512] bf16; flags: [l][g][32]
__global__ __launch_bounds__(256) void lstm_persist(
    const float* __restrict__ Whh_q, const float* __restrict__ Whh_k,
    const float* __restrict__ pre,
    const int* __restrict__ x,
    float* __restrict__ qout, float* __restrict__ kout,
    unsigned short* __restrict__ hbf,
    unsigned int* __restrict__ flags)
{
    __shared__ unsigned short w_lds[64][512];    // 64 KB, 16B-chunk XOR swizzled
    __shared__ unsigned short h_lds[16][512];    // 16 KB, swizzled (row = batch)
    __shared__ float          g_lds[64][17];     // 4.3 KB [gate*16+dd][b_local]
    __shared__ unsigned char  x_lds[16 * TT];    // 8 KB (this group's batches)
    __shared__ float          pre_lds[NTOK][64]; // 3.5 KB [tok][gate*16+dd]

    int wg  = blockIdx.x;
    int l   = wg >> 6;
    int g   = (wg >> 5) & 1;
    int wid = wg & 31;
    int d0  = wid << 4;                          // 16 dims per WG
    int tid = threadIdx.x;
    int lane = tid & 63;
    int rt  = tid >> 6;                          // wave = gate-row tile (rows rt*16..)

    const float* Whh = l ? Whh_k : Whh_q;
    float* hist = l ? kout : qout;
    unsigned short* hb_l = hbf + (size_t)l * 2 * TB * TD;     // [phase][b][dim]
    unsigned int* fl = flags + (l * 2 + g) * 32;              // own group's flags

    // ---- stage W slice: 64 gate-rows (gate*16+dd), f32->bf16, XOR swizzle ----
    {
        int r = tid >> 2;                        // 0..63, 4 threads/row
        const float* src = Whh + (size_t)((r >> 4) * TD + d0 + (r & 15)) * TD;
#pragma unroll
        for (int i = 0; i < 16; ++i) {
            int c = (tid & 3) + 4 * i;           // chunk 0..63 (8 bf16 = 16B)
            float4 a = ((const float4*)src)[c * 2];
            float4 b4 = ((const float4*)src)[c * 2 + 1];
            unsigned short* dst = &w_lds[r][(c ^ (r & 7)) * 8];
            dst[0] = (unsigned short)f2bf(a.x); dst[1] = (unsigned short)f2bf(a.y);
            dst[2] = (unsigned short)f2bf(a.z); dst[3] = (unsigned short)f2bf(a.w);
            dst[4] = (unsigned short)f2bf(b4.x); dst[5] = (unsigned short)f2bf(b4.y);
            dst[6] = (unsigned short)f2bf(b4.z); dst[7] = (unsigned short)f2bf(b4.w);
        }
    }
    for (int i = tid; i < 16 * TT; i += 256)
        x_lds[i] = (unsigned char)x[(g * 16 + (i >> 9)) * TT + (i & 511)];
    for (int i = tid; i < NTOK * 64; i += 256) {
        int tok = i >> 6, j = i & 63;            // j = gate*16 + dd
        pre_lds[tok][j] = pre[((size_t)l * NTOK + tok) * (4 * TD) + (j >> 4) * TD + d0 + (j & 15)];
    }
    __syncthreads();

    int bl = tid >> 4, dd = tid & 15;            // tail mapping (16 b x 16 dd)
    int bg = g * 16 + bl;                        // global batch
    float creg = 0.f;

    // ---- t = 0: tail only (h,c = 0); publish + drain + flag ----
    {
        int tok = x_lds[bl * TT];
        float i_ = fsigmoid(pre_lds[tok][dd]);
        float f_ = fsigmoid(pre_lds[tok][16 + dd]);
        float g_ = ftanh(pre_lds[tok][32 + dd]);
        float o_ = fsigmoid(pre_lds[tok][48 + dd]);
        creg = i_ * g_;
        float h = o_ * ftanh(creg);
        store2_coh(hb_l + (size_t)bg * TD + d0 + dd, f2bf(h));
        hist[((size_t)bg * TT) * TD + d0 + dd] = h;
        asm volatile("s_waitcnt vmcnt(0)" ::: "memory");
    }
    __syncthreads();
    if (tid == 0) store4_coh(fl + wid, 1u);

    for (int t = 1; t < TT; ++t) {
        // ---- phase 1: poll own group's 32 flags (every wave self-gates) ----
        {
            unsigned int need = (unsigned int)t;   // flag==t -> h(t-1) ready
            for (;;) {
                unsigned int v = load4_coh(fl + (lane & 31));
                if (__all((int)(v >= need))) break;
                __builtin_amdgcn_s_sleep(1);
            }
        }
        // ---- phase 2: one clean h(t-1) fetch -> h_lds (deduped, swizzled) ----
        {
            int row = tid >> 4;                    // 0..15 (batch within group)
            const unsigned short* hb = hb_l + (size_t)((t - 1) & 1) * TB * TD
                                            + (size_t)(g * 16 + row) * TD;
            short8 v0 = load16_coh(hb + ((tid & 15) +  0) * 8);
            short8 v1 = load16_coh(hb + ((tid & 15) + 16) * 8);
            short8 v2 = load16_coh(hb + ((tid & 15) + 32) * 8);
            short8 v3 = load16_coh(hb + ((tid & 15) + 48) * 8);
            asm volatile("s_waitcnt vmcnt(0)" ::: "memory");
            __builtin_amdgcn_sched_barrier(0);
            *(short8*)&h_lds[row][(((tid & 15) +  0) ^ (row & 7)) * 8] = v0;
            *(short8*)&h_lds[row][(((tid & 15) + 16) ^ (row & 7)) * 8] = v1;
            *(short8*)&h_lds[row][(((tid & 15) + 32) ^ (row & 7)) * 8] = v2;
            *(short8*)&h_lds[row][(((tid & 15) + 48) ^ (row & 7)) * 8] = v3;
        }
        __syncthreads();

        // ---- phase 3: MFMA, wave rt: 16 gate-rows x 16 batches, K=512 ----
        {
            f32x4 acc = {0.f, 0.f, 0.f, 0.f};
            int rr = rt * 16 + (lane & 15);
            int hr = lane & 15;
#pragma unroll
            for (int kk = 0; kk < 16; ++kk) {
                int c = kk * 4 + (lane >> 4);
                short8 a  = *(const short8*)&h_lds[hr][(c ^ (hr & 7)) * 8];
                short8 bf = *(const short8*)&w_lds[rr][(c ^ (rr & 7)) * 8];
                acc = __builtin_amdgcn_mfma_f32_16x16x32_bf16(a, bf, acc, 0, 0, 0);
            }
            int gb = (lane >> 4) << 2;
#pragma unroll
            for (int r2 = 0; r2 < 4; ++r2) g_lds[rr][gb + r2] = acc[r2];
        }
        __syncthreads();

        // ---- phase 4: tail; publish; drain; flag ----
        {
            int tok = x_lds[bl * TT + t];
            float gi = g_lds[dd][bl]      + pre_lds[tok][dd];
            float gf = g_lds[16 + dd][bl] + pre_lds[tok][16 + dd];
            float gg = g_lds[32 + dd][bl] + pre_lds[tok][32 + dd];
            float go = g_lds[48 + dd][bl] + pre_lds[tok][48 + dd];
            float i_ = fsigmoid(gi), f_ = fsigmoid(gf), g2 = ftanh(gg), o_ = fsigmoid(go);
            creg = f_ * creg + i_ * g2;
            float h = o_ * ftanh(creg);
            store2_coh(hb_l + (size_t)(t & 1) * TB * TD + (size_t)bg * TD + d0 + dd, f2bf(h));
            hist[((size_t)bg * TT + t) * TD + d0 + dd] = h;   // plain cached f32
            asm volatile("s_waitcnt vmcnt(0)" ::: "memory");  // all stores at coherent pt
        }
        __syncthreads();
        if (tid == 0) store4_coh(fl + wid, (unsigned int)(t + 1));
    }
}

// ---- A[b] = q[b] @ k[b]^T, f32, 64x64 tile / WG, 4x4 per thread ----
__global__ __launch_bounds__(256) void qk_gemm(
    const float* __restrict__ q, const float* __restrict__ k, float* __restrict__ A)
{
    __shared__ float qs[64][68];
    __shared__ float ks[64][68];
    int b = blockIdx.y;
    int t0 = (blockIdx.x >> 3) * 64;
    int s0 = (blockIdx.x & 7) * 64;
    const float* qb = q + (size_t)b * TT * TD;
    const float* kb = k + (size_t)b * TT * TD;
    int tid = threadIdx.x;
    int ty = tid >> 4, tx = tid & 15;
    float accr[4][4] = {};
    for (int k0 = 0; k0 < TD; k0 += 64) {
        for (int i = tid; i < 64 * 16; i += 256) {
            int r = i >> 4, c4 = i & 15;
            ((float4*)&qs[r][0])[c4] = ((const float4*)(qb + (size_t)(t0 + r) * TD + k0))[c4];
            ((float4*)&ks[r][0])[c4] = ((const float4*)(kb + (size_t)(s0 + r) * TD + k0))[c4];
        }
        __syncthreads();
#pragma unroll 4
        for (int kk = 0; kk < 64; kk += 4) {
            float4 qv[4], kv[4];
#pragma unroll
            for (int i = 0; i < 4; ++i) qv[i] = *(const float4*)&qs[ty * 4 + i][kk];
#pragma unroll
            for (int j = 0; j < 4; ++j) kv[j] = *(const float4*)&ks[tx * 4 + j][kk];
#pragma unroll
            for (int i = 0; i < 4; ++i)
#pragma unroll
                for (int j = 0; j < 4; ++j)
                    accr[i][j] += qv[i].x * kv[j].x + qv[i].y * kv[j].y
                                + qv[i].z * kv[j].z + qv[i].w * kv[j].w;
        }
        __syncthreads();
    }
    for (int i = 0; i < 4; ++i)
        for (int j = 0; j < 4; ++j)
            A[(size_t)b * TT * TT + (size_t)(t0 + ty * 4 + i) * TT + (s0 + tx * 4 + j)] = accr[i][j];
}

extern "C" void kernel_launch(void* const* d_in, const int* in_sizes, int n_in,
                              void* d_out, int out_size, void* d_ws, size_t ws_size,
                              hipStream_t stream)
{
    const int*   x      = (const int*)d_in[0];
    const float* embed  = (const float*)d_in[1];
    const float* Wih_q  = (const float*)d_in[2];
    const float* Whh_q  = (const float*)d_in[3];
    const float* bih_q  = (const float*)d_in[4];
    const float* bhh_q  = (const float*)d_in[5];
    const float* Wih_k  = (const float*)d_in[6];
    const float* Whh_k  = (const float*)d_in[7];
    const float* bih_k  = (const float*)d_in[8];
    const float* bhh_k  = (const float*)d_in[9];

    float* ws   = (float*)d_ws;
    float* q    = ws;                                   // 8388608 f
    float* kbuf = q + (size_t)TB * TT * TD;             // 8388608 f
    float* pre  = kbuf + (size_t)TB * TT * TD;          // 57344 f
    unsigned short* hbf = (unsigned short*)(pre + 2 * NTOK * 4 * TD);  // 65536 us
    unsigned int* flags = (unsigned int*)(hbf + 65536); // 128 u32

    init_flags<<<1, 128, 0, stream>>>(flags);
    pre_tab_kernel<<<224, 256, 0, stream>>>(embed, Wih_q, bih_q, bhh_q,
                                            Wih_k, bih_k, bhh_k, pre);
    lstm_persist<<<128, 256, 0, stream>>>(Whh_q, Whh_k, pre, x, q, kbuf, hbf, flags);
    dim3 g2(64, 32);
    qk_gemm<<<g2, 256, 0, stream>>>(q, kbuf, (float*)d_out);
}